// Round 1
// 380.349 us; speedup vs baseline: 1.0205x; 1.0205x over previous
//
#include <hip/hip_runtime.h>

// Problem constants
#define DIMD 768
#define NTOK 2048
#define NB   8

typedef __attribute__((ext_vector_type(8))) short bfrag8;
typedef __attribute__((ext_vector_type(4))) float accf4;

// float -> bf16 bits, round-to-nearest-even (finite inputs)
__device__ __forceinline__ unsigned short f2bf(float f) {
  unsigned u = __float_as_uint(f);
  return (unsigned short)((u + 0x7fffu + ((u >> 16) & 1u)) >> 16);
}

// async 16B global -> LDS (wave-uniform base + lane*16 semantics)
__device__ __forceinline__ void glds16(const void* g, void* l) {
  __builtin_amdgcn_global_load_lds(
      (const __attribute__((address_space(1))) void*)g,
      (__attribute__((address_space(3))) void*)l, 16, 0, 0);
}

// ---------------------------------------------------------------------------
// device bodies
// ---------------------------------------------------------------------------

// pack W1|W2 -> Wcat bf16 [768][1536]
__device__ __forceinline__ void packw_body(int blk, const float* __restrict__ W1,
                                           const float* __restrict__ W2,
                                           unsigned short* __restrict__ Wcat) {
  int gid = blk * 256 + threadIdx.x;           // one per 4 elems
  int r = gid / 192, c4 = (gid % 192) * 4;
  float4 a = *(const float4*)(W1 + (size_t)r * DIMD + c4);
  float4 b = *(const float4*)(W2 + (size_t)r * DIMD + c4);
  union { unsigned short us[4]; uint2 u2; } ra, rb;
  ra.us[0] = f2bf(a.x); ra.us[1] = f2bf(a.y); ra.us[2] = f2bf(a.z); ra.us[3] = f2bf(a.w);
  rb.us[0] = f2bf(b.x); rb.us[1] = f2bf(b.y); rb.us[2] = f2bf(b.z); rb.us[3] = f2bf(b.w);
  *(uint2*)(Wcat + (size_t)r * 1536 + c4) = ra.u2;
  *(uint2*)(Wcat + (size_t)r * 1536 + 768 + c4) = rb.u2;
}

// pack x -> bf16 (one thread per 8 floats)
__device__ __forceinline__ void packx_body(int blk, const float* __restrict__ x,
                                           unsigned short* __restrict__ xb) {
  size_t gid = (size_t)blk * 256 + threadIdx.x;
  const float4* x4 = (const float4*)x;
  float4 v0 = x4[gid * 2], v1 = x4[gid * 2 + 1];
  union { unsigned short us[8]; uint4 u4; } r;
  r.us[0] = f2bf(v0.x); r.us[1] = f2bf(v0.y); r.us[2] = f2bf(v0.z); r.us[3] = f2bf(v0.w);
  r.us[4] = f2bf(v1.x); r.us[5] = f2bf(v1.y); r.us[6] = f2bf(v1.z); r.us[7] = f2bf(v1.w);
  ((uint4*)xb)[gid] = r.u4;
}

// BT-format bf16 MFMA GEMM body: C[m][n] = sum_k A[m][k] * B[n][k]
// Tile (64*TMD) x (64*TND), 4 waves, BK=64, glds16 staging, 2-barrier K-loop.
// bid & 7 -> batch (XCD affinity).
// EPI 0: store bf16.
// EPI 1: f32 epilogue gate*acc + gate*(b1+b2) + x (b1v/b2v = biases, xres = residual).
// EPI 2: bf16 store scaled by per-column inv-colsum (b1v = csp partials [b][32][768]).
template <int TMD, int TND, int EPI>
__device__ __forceinline__ void gemm_body(
    unsigned short* As, unsigned short* Bs, int bid,
    const unsigned short* __restrict__ A, const unsigned short* __restrict__ B,
    void* __restrict__ Cout, int K, int lda, int ldb, int ldc, int ntx,
    long long sA, long long sB, long long sC,
    const float* __restrict__ wg, const float* __restrict__ b1v,
    const float* __restrict__ b2v, const float* __restrict__ xres) {
  constexpr int TM = 64 * TMD, TN = 64 * TND;
  __shared__ float csi[64 * TND];      // EPI==2: inv colsum per C column
  const int t = threadIdx.x, w = t >> 6, lane = t & 63;
  const int bz = bid & 7;
  const int r = bid >> 3;
  const int by = r / ntx, bx = r - by * ntx;
  const int m0 = by * TM, n0 = bx * TN;
  const unsigned short* Ab = A + (size_t)bz * sA;
  const unsigned short* Bb = B + (size_t)bz * sB;
  const int srow = lane >> 3;          // 0..7
  const int scol = (lane & 7) * 8;     // element offset within K-slab

  if (EPI == 2) {
    // merge 32 colsum partials -> 1/sum for this block's 128 output columns
    for (int c = t; c < TN; c += 256) {
      const float* cp = b1v + (size_t)bz * 32 * DIMD + n0 + c;
      float s = 0.f;
#pragma unroll
      for (int p = 0; p < 32; ++p) s += cp[(size_t)p * DIMD];
      csi[c] = 1.0f / s;
    }
  }

  accf4 zero = {0.f, 0.f, 0.f, 0.f};
  accf4 acc[2 * TMD][2 * TND];
#pragma unroll
  for (int i = 0; i < 2 * TMD; ++i)
#pragma unroll
    for (int j = 0; j < 2 * TND; ++j) acc[i][j] = zero;

  const int wm = (w & 1) * (32 * TMD), wn = (w >> 1) * (32 * TND);
  const int lm = lane & 15, qd = lane >> 4;

  for (int k0 = 0; k0 < K; k0 += 64) {
    __syncthreads();
#pragma unroll
    for (int l = 0; l < 2 * TND; ++l) {
      int chunk = l * 4 + w;
      int row = chunk * 8 + srow;
      glds16(Bb + (size_t)(n0 + row) * ldb + k0 + scol,
             (char*)Bs + chunk * 1024 + lane * 16);
    }
#pragma unroll
    for (int l = 0; l < 2 * TMD; ++l) {
      int chunk = l * 4 + w;
      int row = chunk * 8 + srow;
      glds16(Ab + (size_t)(m0 + row) * lda + k0 + scol,
             (char*)As + chunk * 1024 + lane * 16);
    }
    __syncthreads();
#pragma unroll
    for (int kc = 0; kc < 2; ++kc) {
      bfrag8 av[2 * TMD], bv[2 * TND];
#pragma unroll
      for (int i = 0; i < 2 * TMD; ++i)
        av[i] = *(const bfrag8*)(As + (wm + i * 16 + lm) * 64 + kc * 32 + qd * 8);
#pragma unroll
      for (int j = 0; j < 2 * TND; ++j)
        bv[j] = *(const bfrag8*)(Bs + (wn + j * 16 + lm) * 64 + kc * 32 + qd * 8);
#pragma unroll
      for (int i = 0; i < 2 * TMD; ++i)
#pragma unroll
        for (int j = 0; j < 2 * TND; ++j)
          acc[i][j] = __builtin_amdgcn_mfma_f32_16x16x32_bf16(av[i], bv[j], acc[i][j], 0, 0, 0);
    }
  }

  if (EPI == 0) {
    unsigned short* Cb = (unsigned short*)Cout + (size_t)bz * sC;
#pragma unroll
    for (int i = 0; i < 2 * TMD; ++i)
#pragma unroll
      for (int j = 0; j < 2 * TND; ++j) {
        int col = n0 + wn + j * 16 + lm;
#pragma unroll
        for (int rr = 0; rr < 4; ++rr) {
          int row = m0 + wm + i * 16 + qd * 4 + rr;
          Cb[(size_t)row * ldc + col] = f2bf(acc[i][j][rr]);
        }
      }
  } else if (EPI == 1) {
    float gate = 1.f / (1.f + __expf(-wg[0]));
    float* Co = (float*)Cout + (size_t)bz * sC;
    const float* Xr = xres + (size_t)bz * sC;
#pragma unroll
    for (int j = 0; j < 2 * TND; ++j) {
      int col = n0 + wn + j * 16 + lm;
      float gb = gate * (b1v[col] + b2v[col]);
#pragma unroll
      for (int i = 0; i < 2 * TMD; ++i)
#pragma unroll
        for (int rr = 0; rr < 4; ++rr) {
          int row = m0 + wm + i * 16 + qd * 4 + rr;
          size_t idx = (size_t)row * ldc + col;
          Co[idx] = gate * acc[i][j][rr] + gb + Xr[idx];
        }
    }
  } else {
    unsigned short* Cb = (unsigned short*)Cout + (size_t)bz * sC;
#pragma unroll
    for (int j = 0; j < 2 * TND; ++j) {
      int lc = wn + j * 16 + lm;
      int col = n0 + lc;
      float ci = csi[lc];
#pragma unroll
      for (int i = 0; i < 2 * TMD; ++i)
#pragma unroll
        for (int rr = 0; rr < 4; ++rr) {
          int row = m0 + wm + i * 16 + qd * 4 + rr;
          Cb[(size_t)row * ldc + col] = f2bf(acc[i][j][rr] * ci);
        }
    }
  }
}

// ---------------------------------------------------------------------------
// kernels
// ---------------------------------------------------------------------------

// prep: pack_w [0,576) | rowsum-inv of exp(x2) [576,4672) | exp(x3) [4672,8768)
// rowsum (feature-axis softmax denom) is per-token: must be applied pre-GEMM,
// so precompute 1/sum here (tiny 64 KB outputs, perfectly coalesced reads).
__global__ __launch_bounds__(256) void prep_kernel(const float* __restrict__ W1,
                                                   const float* __restrict__ W2,
                                                   unsigned short* __restrict__ Wcat,
                                                   const float* __restrict__ x2,
                                                   const float* __restrict__ x3,
                                                   float* __restrict__ rs1,
                                                   float* __restrict__ rs2) {
  int blk = blockIdx.x;
  if (blk < 576) { packw_body(blk, W1, W2, Wcat); return; }
  int rblk = blk - 576;                          // 0..8191
  const float* src = (rblk < 4096) ? x2 : x3;
  float* dst = (rblk < 4096) ? rs1 : rs2;
  int q = rblk & 4095;
  int w = threadIdx.x >> 6, lane = threadIdx.x & 63;
  int row = q * 4 + w;                           // global token 0..16383
  const float* r = src + (size_t)row * DIMD;
  float s = 0.f;
#pragma unroll
  for (int j = 0; j < 12; ++j) s += __expf(r[lane + j * 64]);
#pragma unroll
  for (int off = 32; off; off >>= 1) s += __shfl_xor(s, off, 64);
  if (lane == 0) dst[row] = 1.0f / s;
}

// Fused exp + transpose: Kt = exp*rowsum_inv, Qt = raw exp bits (token-axis
// softmax deferred to S-gemm epilogue). Emits per-(64-token-tile) colsum
// partials csp[b][32][768]. Grid (32, 6, 8 or 16): block = 64 tokens x 128 dims.
__global__ __launch_bounds__(256) void sm_kq(
    const float* __restrict__ xA, const float* __restrict__ rsA,
    unsigned short* __restrict__ KtA, unsigned short* __restrict__ QtA,
    float* __restrict__ cspA,
    const float* __restrict__ xB, const float* __restrict__ rsB,
    unsigned short* __restrict__ KtB, unsigned short* __restrict__ QtB,
    float* __restrict__ cspB) {
  int z = blockIdx.z;
  const float* xin; const float* rsv; unsigned short* Kt; unsigned short* Qt;
  float* csp; int b;
  if (z < 8) { xin = xA; rsv = rsA; Kt = KtA; Qt = QtA; csp = cspA; b = z; }
  else       { xin = xB; rsv = rsB; Kt = KtB; Qt = QtB; csp = cspB; b = z - 8; }
  const int n0 = blockIdx.x * 64, dc = blockIdx.y;
  const int t = threadIdx.x;
  __shared__ float rowsi[64];
  __shared__ __align__(16) unsigned short etile[128 * 72];  // +8 pad: kills 8-way write conflicts
  if (t < 64) rowsi[t] = rsv[(size_t)b * NTOK + n0 + t];
  const float* xbase = xin + ((size_t)b * NTOK + n0) * DIMD + dc * 128;
  const int tok = t >> 2, g0 = t & 3;
#pragma unroll
  for (int p = 0; p < 8; ++p) {
    int dg = g0 + p * 4;                         // 0..31
    float4 v = *(const float4*)(xbase + (size_t)tok * DIMD + dg * 4);
    int dl = dg * 4;
    etile[(dl + 0) * 72 + tok] = f2bf(__expf(v.x));
    etile[(dl + 1) * 72 + tok] = f2bf(__expf(v.y));
    etile[(dl + 2) * 72 + tok] = f2bf(__expf(v.z));
    etile[(dl + 3) * 72 + tok] = f2bf(__expf(v.w));
  }
  __syncthreads();
#pragma unroll
  for (int q = 0; q < 4; ++q) {
    int dl = (t >> 3) + q * 32;                  // 0..127
    int g = t & 7;                               // 8 tokens each
    uint4 e8 = *(const uint4*)(etile + dl * 72 + g * 8);
    float ef[8];
    ef[0] = __uint_as_float(e8.x << 16); ef[1] = __uint_as_float(e8.x & 0xffff0000u);
    ef[2] = __uint_as_float(e8.y << 16); ef[3] = __uint_as_float(e8.y & 0xffff0000u);
    ef[4] = __uint_as_float(e8.z << 16); ef[5] = __uint_as_float(e8.z & 0xffff0000u);
    ef[6] = __uint_as_float(e8.w << 16); ef[7] = __uint_as_float(e8.w & 0xffff0000u);
    float4 r0 = *(const float4*)&rowsi[g * 8];
    float4 r1 = *(const float4*)&rowsi[g * 8 + 4];
    union { unsigned short us[8]; uint4 u4; } ko;
    ko.us[0] = f2bf(ef[0] * r0.x); ko.us[1] = f2bf(ef[1] * r0.y);
    ko.us[2] = f2bf(ef[2] * r0.z); ko.us[3] = f2bf(ef[3] * r0.w);
    ko.us[4] = f2bf(ef[4] * r1.x); ko.us[5] = f2bf(ef[5] * r1.y);
    ko.us[6] = f2bf(ef[6] * r1.z); ko.us[7] = f2bf(ef[7] * r1.w);
    size_t orow = ((size_t)b * DIMD + dc * 128 + dl) * NTOK + n0 + g * 8;
    *(uint4*)(Kt + orow) = ko.u4;
    *(uint4*)(Qt + orow) = e8;                   // raw exp bits
    // colsum partial over this tile's 64 tokens for dim dl
    float s = ((ef[0] + ef[1]) + (ef[2] + ef[3])) + ((ef[4] + ef[5]) + (ef[6] + ef[7]));
    s += __shfl_xor(s, 1, 64);
    s += __shfl_xor(s, 2, 64);
    s += __shfl_xor(s, 4, 64);
    if (g == 0) csp[((size_t)b * 32 + blockIdx.x) * DIMD + dc * 128 + dl] = s;
  }
}

// standalone GEMM (final epilogue)
template <int TMD, int TND, int EPI>
__global__ __launch_bounds__(256) void mfma_bt(
    const unsigned short* __restrict__ A, const unsigned short* __restrict__ B,
    void* __restrict__ Cout, int K, int lda, int ldb, int ldc, int ntx,
    long long sA, long long sB, long long sC,
    const float* __restrict__ wg, const float* __restrict__ b1v,
    const float* __restrict__ b2v, const float* __restrict__ xres) {
  __shared__ __align__(16) unsigned short As[64 * TMD * 64];
  __shared__ __align__(16) unsigned short Bs[64 * TND * 64];
  gemm_body<TMD, TND, EPI>(As, Bs, blockIdx.x, A, B, Cout, K, lda, ldb, ldc, ntx,
                           sA, sB, sC, wg, b1v, b2v, xres);
}

// S-gemm (both attentions in one launch when grid=576): blocks [0,288) do
// S_a = Kta . Qta^T * diag(cspa^-1); [288,576) do S_b -> Cb.
__global__ __launch_bounds__(256) void sgemm_s(
    const unsigned short* __restrict__ KtA, const unsigned short* __restrict__ QtA,
    const float* __restrict__ cspA,
    const unsigned short* __restrict__ KtB, const unsigned short* __restrict__ QtB,
    const float* __restrict__ cspB,
    unsigned short* __restrict__ Ca, unsigned short* __restrict__ Cb) {
  __shared__ __align__(16) unsigned short As[128 * 64];
  __shared__ __align__(16) unsigned short Bs[128 * 64];
  bool second = blockIdx.x >= 288;
  const unsigned short* A = second ? KtB : KtA;
  const unsigned short* B = second ? QtB : QtA;
  const float* csp = second ? cspB : cspA;
  unsigned short* C = second ? Cb : Ca;
  int blk = second ? (blockIdx.x - 288) : blockIdx.x;
  gemm_body<2, 2, 2>(As, Bs, blk, A, B, C, NTOK, NTOK, NTOK, 1536, 6,
                     768LL * NTOK, 768LL * NTOK, 768LL * 1536,
                     nullptr, csp, nullptr, nullptr);
}

// s2 (Bt = Wcat . Scat^T, 288 blocks, 128x128) + pack_x (6144 BW-bound blocks)
__global__ __launch_bounds__(256) void s2_packx_kernel(
    const unsigned short* __restrict__ Wcat, const unsigned short* __restrict__ Scat,
    unsigned short* __restrict__ Bt, const float* __restrict__ x,
    unsigned short* __restrict__ xb) {
  __shared__ __align__(16) unsigned short As[128 * 64];
  __shared__ __align__(16) unsigned short Bs[128 * 64];
  int blk = blockIdx.x;
  if (blk < 288) {
    gemm_body<2, 2, 0>(As, Bs, blk, Wcat, Scat, Bt, 1536, 1536, 1536, 768, 6,
                       0LL, 768LL * 1536, 768LL * 768,
                       nullptr, nullptr, nullptr, nullptr);
  } else {
    packx_body(blk - 288, x, xb);
  }
}

// ---------------------------------------------------------------------------
// launch
// ---------------------------------------------------------------------------
extern "C" void kernel_launch(void* const* d_in, const int* in_sizes, int n_in,
                              void* d_out, int out_size, void* d_ws, size_t ws_size,
                              hipStream_t stream) {
  const float* x  = (const float*)d_in[0];
  const float* x2 = (const float*)d_in[1];
  const float* x3 = (const float*)d_in[2];
  const float* W1 = (const float*)d_in[3];
  const float* b1 = (const float*)d_in[4];
  const float* W2 = (const float*)d_in[5];
  const float* b2 = (const float*)d_in[6];
  const float* w  = (const float*)d_in[7];
  float* out = (float*)d_out;
  char* ws = (char*)d_ws;

  dim3 blk(256);
  const bool merged = ws_size >= 123600896ull;

  if (merged) {
    // layout (bytes): Kt1 0 | Qt1 25165824 | Kt2 50331648 | Qt2 75497472 |
    // Scat 100663296 | Wcat 119537664 | csp1 121896960 | csp2 122683392 |
    // rs1 123469824 | rs2 123535360 | end 123600896
    // Bt aliases Kt1 (dead after sgemm_s); xb aliases Kt1+9437184.
    unsigned short* Kt1  = (unsigned short*)(ws + 0);
    unsigned short* Qt1  = (unsigned short*)(ws + 25165824);
    unsigned short* Kt2  = (unsigned short*)(ws + 50331648);
    unsigned short* Qt2  = (unsigned short*)(ws + 75497472);
    unsigned short* Scat = (unsigned short*)(ws + 100663296);
    unsigned short* Wcat = (unsigned short*)(ws + 119537664);
    float* csp1 = (float*)(ws + 121896960);
    float* csp2 = (float*)(ws + 122683392);
    float* rs1  = (float*)(ws + 123469824);
    float* rs2  = (float*)(ws + 123535360);
    unsigned short* Bt = (unsigned short*)(ws + 0);
    unsigned short* xb = (unsigned short*)(ws + 9437184);

    prep_kernel<<<8768, blk, 0, stream>>>(W1, W2, Wcat, x2, x3, rs1, rs2);
    sm_kq<<<dim3(32, 6, 16), blk, 0, stream>>>(x2, rs1, Kt1, Qt1, csp1,
                                               x3, rs2, Kt2, Qt2, csp2);
    sgemm_s<<<576, blk, 0, stream>>>(Kt1, Qt1, csp1, Kt2, Qt2, csp2, Scat, Scat + 768);
    s2_packx_kernel<<<6432, blk, 0, stream>>>(Wcat, Scat, Bt, x, xb);
    mfma_bt<2, 2, 1><<<768, blk, 0, stream>>>(xb, Bt, out, DIMD, DIMD, DIMD, DIMD, 6,
                                              (long long)NTOK * DIMD, 768LL * 768,
                                              (long long)NTOK * DIMD, w, b1, b2, x);
  } else {
    // sequential fallback within the proven 107 MB footprint:
    // Kt 0 | Qt 25165824 | Scat 50331648 | Bt 69206016 | xb 78643200 |
    // Wcat 103809024 (end 106168320). csp/rs alias the Bt region (dead until s2).
    unsigned short* Kt   = (unsigned short*)(ws + 0);
    unsigned short* Qt   = (unsigned short*)(ws + 25165824);
    unsigned short* Scat = (unsigned short*)(ws + 50331648);
    unsigned short* Bt   = (unsigned short*)(ws + 69206016);
    float* csp1 = (float*)(ws + 69206016);
    float* csp2 = (float*)(ws + 69992448);
    float* rs1  = (float*)(ws + 70778880);
    float* rs2  = (float*)(ws + 70844416);
    unsigned short* xb   = (unsigned short*)(ws + 78643200);
    unsigned short* Wcat = (unsigned short*)(ws + 103809024);

    prep_kernel<<<8768, blk, 0, stream>>>(W1, W2, Wcat, x2, x3, rs1, rs2);
    sm_kq<<<dim3(32, 6, 8), blk, 0, stream>>>(x2, rs1, Kt, Qt, csp1,
                                              x2, rs1, Kt, Qt, csp1);
    sgemm_s<<<288, blk, 0, stream>>>(Kt, Qt, csp1, Kt, Qt, csp1, Scat, Scat);
    sm_kq<<<dim3(32, 6, 8), blk, 0, stream>>>(x3, rs2, Kt, Qt, csp2,
                                              x3, rs2, Kt, Qt, csp2);
    sgemm_s<<<288, blk, 0, stream>>>(Kt, Qt, csp2, Kt, Qt, csp2, Scat + 768, Scat + 768);
    s2_packx_kernel<<<6432, blk, 0, stream>>>(Wcat, Scat, Bt, x, xb);
    mfma_bt<2, 2, 1><<<768, blk, 0, stream>>>(xb, Bt, out, DIMD, DIMD, DIMD, DIMD, 6,
                                              (long long)NTOK * DIMD, 768LL * 768,
                                              (long long)NTOK * DIMD, w, b1, b2, x);
  }
}

// Round 2
// 356.246 us; speedup vs baseline: 1.0895x; 1.0677x over previous
//
#include <hip/hip_runtime.h>

// Problem constants
#define DIMD 768
#define NTOK 2048
#define NB   8

typedef __attribute__((ext_vector_type(8))) short bfrag8;
typedef __attribute__((ext_vector_type(4))) float accf4;

// float -> bf16 bits, round-to-nearest-even (finite inputs)
__device__ __forceinline__ unsigned short f2bf(float f) {
  unsigned u = __float_as_uint(f);
  return (unsigned short)((u + 0x7fffu + ((u >> 16) & 1u)) >> 16);
}

// async 16B global -> LDS (wave-uniform base + lane*16 semantics)
__device__ __forceinline__ void glds16(const void* g, void* l) {
  __builtin_amdgcn_global_load_lds(
      (const __attribute__((address_space(1))) void*)g,
      (__attribute__((address_space(3))) void*)l, 16, 0, 0);
}

// ---------------------------------------------------------------------------
// device bodies
// ---------------------------------------------------------------------------

// pack W1|W2 -> Wcat bf16 [768][1536]
__device__ __forceinline__ void packw_body(int blk, const float* __restrict__ W1,
                                           const float* __restrict__ W2,
                                           unsigned short* __restrict__ Wcat) {
  int gid = blk * 256 + threadIdx.x;           // one per 4 elems
  int r = gid / 192, c4 = (gid % 192) * 4;
  float4 a = *(const float4*)(W1 + (size_t)r * DIMD + c4);
  float4 b = *(const float4*)(W2 + (size_t)r * DIMD + c4);
  union { unsigned short us[4]; uint2 u2; } ra, rb;
  ra.us[0] = f2bf(a.x); ra.us[1] = f2bf(a.y); ra.us[2] = f2bf(a.z); ra.us[3] = f2bf(a.w);
  rb.us[0] = f2bf(b.x); rb.us[1] = f2bf(b.y); rb.us[2] = f2bf(b.z); rb.us[3] = f2bf(b.w);
  *(uint2*)(Wcat + (size_t)r * 1536 + c4) = ra.u2;
  *(uint2*)(Wcat + (size_t)r * 1536 + 768 + c4) = rb.u2;
}

// pack x -> bf16 (one thread per 8 floats)
__device__ __forceinline__ void packx_body(int blk, const float* __restrict__ x,
                                           unsigned short* __restrict__ xb) {
  size_t gid = (size_t)blk * 256 + threadIdx.x;
  const float4* x4 = (const float4*)x;
  float4 v0 = x4[gid * 2], v1 = x4[gid * 2 + 1];
  union { unsigned short us[8]; uint4 u4; } r;
  r.us[0] = f2bf(v0.x); r.us[1] = f2bf(v0.y); r.us[2] = f2bf(v0.z); r.us[3] = f2bf(v0.w);
  r.us[4] = f2bf(v1.x); r.us[5] = f2bf(v1.y); r.us[6] = f2bf(v1.z); r.us[7] = f2bf(v1.w);
  ((uint4*)xb)[gid] = r.u4;
}

// BT-format bf16 MFMA GEMM body: C[m][n] = sum_k A[m][k] * B[n][k]
// Tile (64*TMD) x (64*TND), 4 waves, BK=64, glds16 staging.
// Double-buffered LDS + single fused "s_waitcnt vmcnt(0); s_barrier" per
// K-step (T3/T4-minimum recipe): next tile's loads are issued BEFORE the
// current tile's compute, and drained only after the MFMA cluster, so the
// HBM/L2 latency hides under ds_read+MFMA instead of being a cold stall.
// bid & 7 -> batch (XCD affinity).
// EPI 0: store bf16.
// EPI 1: f32 epilogue gate*acc + gate*(b1+b2) + x.
// EPI 2: bf16 store scaled by per-column inv-colsum (b1v = csp partials [b][32][768]).
template <int TMD, int TND, int EPI>
__device__ __forceinline__ void gemm_body(
    unsigned short* As, unsigned short* Bs, int bid,
    const unsigned short* __restrict__ A, const unsigned short* __restrict__ B,
    void* __restrict__ Cout, int K, int lda, int ldb, int ldc, int ntx,
    long long sA, long long sB, long long sC,
    const float* __restrict__ wg, const float* __restrict__ b1v,
    const float* __restrict__ b2v, const float* __restrict__ xres) {
  constexpr int TM = 64 * TMD, TN = 64 * TND;
  constexpr int ASZ = TM * 64, BSZ = TN * 64;  // shorts per LDS buffer
  __shared__ float csi[64 * TND];              // EPI==2: inv colsum per C column
  const int t = threadIdx.x, w = t >> 6, lane = t & 63;
  const int bz = bid & 7;
  const int r = bid >> 3;
  const int by = r / ntx, bx = r - by * ntx;
  const int m0 = by * TM, n0 = bx * TN;
  const unsigned short* Ab = A + (size_t)bz * sA;
  const unsigned short* Bb = B + (size_t)bz * sB;
  const int srow = lane >> 3;          // 0..7
  const int scol = (lane & 7) * 8;     // element offset within K-slab

  auto stage = [&](int buf, int k0) {
    unsigned short* Ad = As + buf * ASZ;
    unsigned short* Bd = Bs + buf * BSZ;
#pragma unroll
    for (int l = 0; l < 2 * TND; ++l) {
      int chunk = l * 4 + w;
      int row = chunk * 8 + srow;
      glds16(Bb + (size_t)(n0 + row) * ldb + k0 + scol,
             (char*)Bd + chunk * 1024 + lane * 16);
    }
#pragma unroll
    for (int l = 0; l < 2 * TMD; ++l) {
      int chunk = l * 4 + w;
      int row = chunk * 8 + srow;
      glds16(Ab + (size_t)(m0 + row) * lda + k0 + scol,
             (char*)Ad + chunk * 1024 + lane * 16);
    }
  };

  stage(0, 0);

  if (EPI == 2) {
    // merge 32 colsum partials -> 1/sum for this block's output columns
    for (int c = t; c < TN; c += 256) {
      const float* cp = b1v + (size_t)bz * 32 * DIMD + n0 + c;
      float s = 0.f;
#pragma unroll
      for (int p = 0; p < 32; ++p) s += cp[(size_t)p * DIMD];
      csi[c] = 1.0f / s;
    }
  }

  accf4 zero = {0.f, 0.f, 0.f, 0.f};
  accf4 acc[2 * TMD][2 * TND];
#pragma unroll
  for (int i = 0; i < 2 * TMD; ++i)
#pragma unroll
    for (int j = 0; j < 2 * TND; ++j) acc[i][j] = zero;

  const int wm = (w & 1) * (32 * TMD), wn = (w >> 1) * (32 * TND);
  const int lm = lane & 15, qd = lane >> 4;

  // drains stage(0) (syncthreads implies vmcnt(0)+lgkmcnt(0)) and makes csi visible
  __syncthreads();

  const int nt = K / 64;
  int cur = 0;
#pragma unroll 2
  for (int tt = 0; tt < nt; ++tt) {
    if (tt + 1 < nt) stage(cur ^ 1, (tt + 1) * 64);
    const unsigned short* Ar = As + cur * ASZ;
    const unsigned short* Br = Bs + cur * BSZ;
#pragma unroll
    for (int kc = 0; kc < 2; ++kc) {
      bfrag8 av[2 * TMD], bv[2 * TND];
#pragma unroll
      for (int i = 0; i < 2 * TMD; ++i)
        av[i] = *(const bfrag8*)(Ar + (wm + i * 16 + lm) * 64 + kc * 32 + qd * 8);
#pragma unroll
      for (int j = 0; j < 2 * TND; ++j)
        bv[j] = *(const bfrag8*)(Br + (wn + j * 16 + lm) * 64 + kc * 32 + qd * 8);
      __builtin_amdgcn_s_setprio(1);
#pragma unroll
      for (int i = 0; i < 2 * TMD; ++i)
#pragma unroll
        for (int j = 0; j < 2 * TND; ++j)
          acc[i][j] = __builtin_amdgcn_mfma_f32_16x16x32_bf16(av[i], bv[j], acc[i][j], 0, 0, 0);
      __builtin_amdgcn_s_setprio(0);
    }
    if (tt + 1 < nt) {
      // fused: wait own stage loads, then workgroup barrier. All ds_reads of
      // buf[cur] were consumed by MFMAs above, so buf[cur] is free to restage.
      asm volatile("s_waitcnt vmcnt(0)\n\ts_barrier" ::: "memory");
    }
    cur ^= 1;
  }

  if (EPI == 0) {
    unsigned short* Cb = (unsigned short*)Cout + (size_t)bz * sC;
#pragma unroll
    for (int i = 0; i < 2 * TMD; ++i)
#pragma unroll
      for (int j = 0; j < 2 * TND; ++j) {
        int col = n0 + wn + j * 16 + lm;
#pragma unroll
        for (int rr = 0; rr < 4; ++rr) {
          int row = m0 + wm + i * 16 + qd * 4 + rr;
          Cb[(size_t)row * ldc + col] = f2bf(acc[i][j][rr]);
        }
      }
  } else if (EPI == 1) {
    float gate = 1.f / (1.f + __expf(-wg[0]));
    float* Co = (float*)Cout + (size_t)bz * sC;
    const float* Xr = xres + (size_t)bz * sC;
#pragma unroll
    for (int j = 0; j < 2 * TND; ++j) {
      int col = n0 + wn + j * 16 + lm;
      float gb = gate * (b1v[col] + b2v[col]);
#pragma unroll
      for (int i = 0; i < 2 * TMD; ++i)
#pragma unroll
        for (int rr = 0; rr < 4; ++rr) {
          int row = m0 + wm + i * 16 + qd * 4 + rr;
          size_t idx = (size_t)row * ldc + col;
          Co[idx] = gate * acc[i][j][rr] + gb + Xr[idx];
        }
    }
  } else {
    unsigned short* Cb = (unsigned short*)Cout + (size_t)bz * sC;
#pragma unroll
    for (int j = 0; j < 2 * TND; ++j) {
      int lc = wn + j * 16 + lm;
      int col = n0 + lc;
      float ci = csi[lc];
#pragma unroll
      for (int i = 0; i < 2 * TMD; ++i)
#pragma unroll
        for (int rr = 0; rr < 4; ++rr) {
          int row = m0 + wm + i * 16 + qd * 4 + rr;
          Cb[(size_t)row * ldc + col] = f2bf(acc[i][j][rr] * ci);
        }
    }
  }
}

// ---------------------------------------------------------------------------
// kernels
// ---------------------------------------------------------------------------

// prep: pack_w [0,576) | rowsum-inv of exp(x2) [576,4672) | exp(x3) [4672,8768)
__global__ __launch_bounds__(256) void prep_kernel(const float* __restrict__ W1,
                                                   const float* __restrict__ W2,
                                                   unsigned short* __restrict__ Wcat,
                                                   const float* __restrict__ x2,
                                                   const float* __restrict__ x3,
                                                   float* __restrict__ rs1,
                                                   float* __restrict__ rs2) {
  int blk = blockIdx.x;
  if (blk < 576) { packw_body(blk, W1, W2, Wcat); return; }
  int rblk = blk - 576;                          // 0..8191
  const float* src = (rblk < 4096) ? x2 : x3;
  float* dst = (rblk < 4096) ? rs1 : rs2;
  int q = rblk & 4095;
  int w = threadIdx.x >> 6, lane = threadIdx.x & 63;
  int row = q * 4 + w;                           // global token 0..16383
  const float* r = src + (size_t)row * DIMD;
  float s = 0.f;
#pragma unroll
  for (int j = 0; j < 12; ++j) s += __expf(r[lane + j * 64]);
#pragma unroll
  for (int off = 32; off; off >>= 1) s += __shfl_xor(s, off, 64);
  if (lane == 0) dst[row] = 1.0f / s;
}

// Fused exp + transpose: Kt = exp*rowsum_inv, Qt = raw exp bits (token-axis
// softmax deferred to S-gemm epilogue). Emits per-(64-token-tile) colsum
// partials csp[b][32][768]. Grid (32, 6, 8 or 16): block = 64 tokens x 128 dims.
__global__ __launch_bounds__(256) void sm_kq(
    const float* __restrict__ xA, const float* __restrict__ rsA,
    unsigned short* __restrict__ KtA, unsigned short* __restrict__ QtA,
    float* __restrict__ cspA,
    const float* __restrict__ xB, const float* __restrict__ rsB,
    unsigned short* __restrict__ KtB, unsigned short* __restrict__ QtB,
    float* __restrict__ cspB) {
  int z = blockIdx.z;
  const float* xin; const float* rsv; unsigned short* Kt; unsigned short* Qt;
  float* csp; int b;
  if (z < 8) { xin = xA; rsv = rsA; Kt = KtA; Qt = QtA; csp = cspA; b = z; }
  else       { xin = xB; rsv = rsB; Kt = KtB; Qt = QtB; csp = cspB; b = z - 8; }
  const int n0 = blockIdx.x * 64, dc = blockIdx.y;
  const int t = threadIdx.x;
  __shared__ float rowsi[64];
  __shared__ __align__(16) unsigned short etile[128 * 72];  // +8 pad: kills write conflicts
  if (t < 64) rowsi[t] = rsv[(size_t)b * NTOK + n0 + t];
  const float* xbase = xin + ((size_t)b * NTOK + n0) * DIMD + dc * 128;
  const int tok = t >> 2, g0 = t & 3;
#pragma unroll
  for (int p = 0; p < 8; ++p) {
    int dg = g0 + p * 4;                         // 0..31
    float4 v = *(const float4*)(xbase + (size_t)tok * DIMD + dg * 4);
    int dl = dg * 4;
    etile[(dl + 0) * 72 + tok] = f2bf(__expf(v.x));
    etile[(dl + 1) * 72 + tok] = f2bf(__expf(v.y));
    etile[(dl + 2) * 72 + tok] = f2bf(__expf(v.z));
    etile[(dl + 3) * 72 + tok] = f2bf(__expf(v.w));
  }
  __syncthreads();
#pragma unroll
  for (int q = 0; q < 4; ++q) {
    int dl = (t >> 3) + q * 32;                  // 0..127
    int g = t & 7;                               // 8 tokens each
    uint4 e8 = *(const uint4*)(etile + dl * 72 + g * 8);
    float ef[8];
    ef[0] = __uint_as_float(e8.x << 16); ef[1] = __uint_as_float(e8.x & 0xffff0000u);
    ef[2] = __uint_as_float(e8.y << 16); ef[3] = __uint_as_float(e8.y & 0xffff0000u);
    ef[4] = __uint_as_float(e8.z << 16); ef[5] = __uint_as_float(e8.z & 0xffff0000u);
    ef[6] = __uint_as_float(e8.w << 16); ef[7] = __uint_as_float(e8.w & 0xffff0000u);
    float4 r0 = *(const float4*)&rowsi[g * 8];
    float4 r1 = *(const float4*)&rowsi[g * 8 + 4];
    union { unsigned short us[8]; uint4 u4; } ko;
    ko.us[0] = f2bf(ef[0] * r0.x); ko.us[1] = f2bf(ef[1] * r0.y);
    ko.us[2] = f2bf(ef[2] * r0.z); ko.us[3] = f2bf(ef[3] * r0.w);
    ko.us[4] = f2bf(ef[4] * r1.x); ko.us[5] = f2bf(ef[5] * r1.y);
    ko.us[6] = f2bf(ef[6] * r1.z); ko.us[7] = f2bf(ef[7] * r1.w);
    size_t orow = ((size_t)b * DIMD + dc * 128 + dl) * NTOK + n0 + g * 8;
    *(uint4*)(Kt + orow) = ko.u4;
    *(uint4*)(Qt + orow) = e8;                   // raw exp bits
    float s = ((ef[0] + ef[1]) + (ef[2] + ef[3])) + ((ef[4] + ef[5]) + (ef[6] + ef[7]));
    s += __shfl_xor(s, 1, 64);
    s += __shfl_xor(s, 2, 64);
    s += __shfl_xor(s, 4, 64);
    if (g == 0) csp[((size_t)b * 32 + blockIdx.x) * DIMD + dc * 128 + dl] = s;
  }
}

// standalone GEMM (final epilogue)
template <int TMD, int TND, int EPI>
__global__ __launch_bounds__(256) void mfma_bt(
    const unsigned short* __restrict__ A, const unsigned short* __restrict__ B,
    void* __restrict__ Cout, int K, int lda, int ldb, int ldc, int ntx,
    long long sA, long long sB, long long sC,
    const float* __restrict__ wg, const float* __restrict__ b1v,
    const float* __restrict__ b2v, const float* __restrict__ xres) {
  __shared__ __align__(16) unsigned short As[2 * 64 * TMD * 64];
  __shared__ __align__(16) unsigned short Bs[2 * 64 * TND * 64];
  gemm_body<TMD, TND, EPI>(As, Bs, blockIdx.x, A, B, Cout, K, lda, ldb, ldc, ntx,
                           sA, sB, sC, wg, b1v, b2v, xres);
}

// S-gemm (both attentions in one launch when grid=576): blocks [0,288) do
// S_a = Kta . Qta^T * diag(cspa^-1); [288,576) do S_b -> Cb.
__global__ __launch_bounds__(256) void sgemm_s(
    const unsigned short* __restrict__ KtA, const unsigned short* __restrict__ QtA,
    const float* __restrict__ cspA,
    const unsigned short* __restrict__ KtB, const unsigned short* __restrict__ QtB,
    const float* __restrict__ cspB,
    unsigned short* __restrict__ Ca, unsigned short* __restrict__ Cb) {
  __shared__ __align__(16) unsigned short As[2 * 128 * 64];
  __shared__ __align__(16) unsigned short Bs[2 * 128 * 64];
  bool second = blockIdx.x >= 288;
  const unsigned short* A = second ? KtB : KtA;
  const unsigned short* B = second ? QtB : QtA;
  const float* csp = second ? cspB : cspA;
  unsigned short* C = second ? Cb : Ca;
  int blk = second ? (blockIdx.x - 288) : blockIdx.x;
  gemm_body<2, 2, 2>(As, Bs, blk, A, B, C, NTOK, NTOK, NTOK, 1536, 6,
                     768LL * NTOK, 768LL * NTOK, 768LL * 1536,
                     nullptr, csp, nullptr, nullptr);
}

// s2 (Bt = Wcat . Scat^T, 288 blocks, 128x128) + pack_x (6144 BW-bound blocks)
__global__ __launch_bounds__(256) void s2_packx_kernel(
    const unsigned short* __restrict__ Wcat, const unsigned short* __restrict__ Scat,
    unsigned short* __restrict__ Bt, const float* __restrict__ x,
    unsigned short* __restrict__ xb) {
  __shared__ __align__(16) unsigned short As[2 * 128 * 64];
  __shared__ __align__(16) unsigned short Bs[2 * 128 * 64];
  int blk = blockIdx.x;
  if (blk < 288) {
    gemm_body<2, 2, 0>(As, Bs, blk, Wcat, Scat, Bt, 1536, 1536, 1536, 768, 6,
                       0LL, 768LL * 1536, 768LL * 768,
                       nullptr, nullptr, nullptr, nullptr);
  } else {
    packx_body(blk - 288, x, xb);
  }
}

// ---------------------------------------------------------------------------
// launch
// ---------------------------------------------------------------------------
extern "C" void kernel_launch(void* const* d_in, const int* in_sizes, int n_in,
                              void* d_out, int out_size, void* d_ws, size_t ws_size,
                              hipStream_t stream) {
  const float* x  = (const float*)d_in[0];
  const float* x2 = (const float*)d_in[1];
  const float* x3 = (const float*)d_in[2];
  const float* W1 = (const float*)d_in[3];
  const float* b1 = (const float*)d_in[4];
  const float* W2 = (const float*)d_in[5];
  const float* b2 = (const float*)d_in[6];
  const float* w  = (const float*)d_in[7];
  float* out = (float*)d_out;
  char* ws = (char*)d_ws;

  dim3 blk(256);
  const bool merged = ws_size >= 123600896ull;

  if (merged) {
    // layout (bytes): Kt1 0 | Qt1 25165824 | Kt2 50331648 | Qt2 75497472 |
    // Scat 100663296 | Wcat 119537664 | csp1 121896960 | csp2 122683392 |
    // rs1 123469824 | rs2 123535360 | end 123600896
    // Bt aliases Kt1 (dead after sgemm_s); xb aliases Kt1+9437184.
    unsigned short* Kt1  = (unsigned short*)(ws + 0);
    unsigned short* Qt1  = (unsigned short*)(ws + 25165824);
    unsigned short* Kt2  = (unsigned short*)(ws + 50331648);
    unsigned short* Qt2  = (unsigned short*)(ws + 75497472);
    unsigned short* Scat = (unsigned short*)(ws + 100663296);
    unsigned short* Wcat = (unsigned short*)(ws + 119537664);
    float* csp1 = (float*)(ws + 121896960);
    float* csp2 = (float*)(ws + 122683392);
    float* rs1  = (float*)(ws + 123469824);
    float* rs2  = (float*)(ws + 123535360);
    unsigned short* Bt = (unsigned short*)(ws + 0);
    unsigned short* xb = (unsigned short*)(ws + 9437184);

    prep_kernel<<<8768, blk, 0, stream>>>(W1, W2, Wcat, x2, x3, rs1, rs2);
    sm_kq<<<dim3(32, 6, 16), blk, 0, stream>>>(x2, rs1, Kt1, Qt1, csp1,
                                               x3, rs2, Kt2, Qt2, csp2);
    sgemm_s<<<576, blk, 0, stream>>>(Kt1, Qt1, csp1, Kt2, Qt2, csp2, Scat, Scat + 768);
    s2_packx_kernel<<<6432, blk, 0, stream>>>(Wcat, Scat, Bt, x, xb);
    mfma_bt<2, 2, 1><<<768, blk, 0, stream>>>(xb, Bt, out, DIMD, DIMD, DIMD, DIMD, 6,
                                              (long long)NTOK * DIMD, 768LL * 768,
                                              (long long)NTOK * DIMD, w, b1, b2, x);
  } else {
    // sequential fallback within the proven 107 MB footprint:
    // Kt 0 | Qt 25165824 | Scat 50331648 | Bt 69206016 | xb 78643200 |
    // Wcat 103809024 (end 106168320). csp/rs alias the Bt region (dead until s2).
    unsigned short* Kt   = (unsigned short*)(ws + 0);
    unsigned short* Qt   = (unsigned short*)(ws + 25165824);
    unsigned short* Scat = (unsigned short*)(ws + 50331648);
    unsigned short* Bt   = (unsigned short*)(ws + 69206016);
    float* csp1 = (float*)(ws + 69206016);
    float* csp2 = (float*)(ws + 69992448);
    float* rs1  = (float*)(ws + 70778880);
    float* rs2  = (float*)(ws + 70844416);
    unsigned short* xb   = (unsigned short*)(ws + 78643200);
    unsigned short* Wcat = (unsigned short*)(ws + 103809024);

    prep_kernel<<<8768, blk, 0, stream>>>(W1, W2, Wcat, x2, x3, rs1, rs2);
    sm_kq<<<dim3(32, 6, 8), blk, 0, stream>>>(x2, rs1, Kt, Qt, csp1,
                                              x2, rs1, Kt, Qt, csp1);
    sgemm_s<<<288, blk, 0, stream>>>(Kt, Qt, csp1, Kt, Qt, csp1, Scat, Scat);
    sm_kq<<<dim3(32, 6, 8), blk, 0, stream>>>(x3, rs2, Kt, Qt, csp2,
                                              x3, rs2, Kt, Qt, csp2);
    sgemm_s<<<288, blk, 0, stream>>>(Kt, Qt, csp2, Kt, Qt, csp2, Scat + 768, Scat + 768);
    s2_packx_kernel<<<6432, blk, 0, stream>>>(Wcat, Scat, Bt, x, xb);
    mfma_bt<2, 2, 1><<<768, blk, 0, stream>>>(xb, Bt, out, DIMD, DIMD, DIMD, DIMD, 6,
                                              (long long)NTOK * DIMD, 768LL * 768,
                                              (long long)NTOK * DIMD, w, b1, b2, x);
  }
}

// Round 3
// 323.004 us; speedup vs baseline: 1.2017x; 1.1029x over previous
//
#include <hip/hip_runtime.h>

// Problem constants
#define DIMD 768
#define NTOK 2048
#define NB   8

typedef __attribute__((ext_vector_type(8))) short bfrag8;
typedef __attribute__((ext_vector_type(4))) float accf4;

// float -> bf16 bits, round-to-nearest-even (finite inputs)
__device__ __forceinline__ unsigned short f2bf(float f) {
  unsigned u = __float_as_uint(f);
  return (unsigned short)((u + 0x7fffu + ((u >> 16) & 1u)) >> 16);
}

// async 16B global -> LDS (wave-uniform base + lane*16 semantics)
__device__ __forceinline__ void glds16(const void* g, void* l) {
  __builtin_amdgcn_global_load_lds(
      (const __attribute__((address_space(1))) void*)g,
      (__attribute__((address_space(3))) void*)l, 16, 0, 0);
}

// ---------------------------------------------------------------------------
// device bodies
// ---------------------------------------------------------------------------

// pack W1|W2 -> Wcat bf16 [768][1536]
__device__ __forceinline__ void packw_body(int blk, const float* __restrict__ W1,
                                           const float* __restrict__ W2,
                                           unsigned short* __restrict__ Wcat) {
  int gid = blk * 256 + threadIdx.x;           // one per 4 elems
  int r = gid / 192, c4 = (gid % 192) * 4;
  float4 a = *(const float4*)(W1 + (size_t)r * DIMD + c4);
  float4 b = *(const float4*)(W2 + (size_t)r * DIMD + c4);
  union { unsigned short us[4]; uint2 u2; } ra, rb;
  ra.us[0] = f2bf(a.x); ra.us[1] = f2bf(a.y); ra.us[2] = f2bf(a.z); ra.us[3] = f2bf(a.w);
  rb.us[0] = f2bf(b.x); rb.us[1] = f2bf(b.y); rb.us[2] = f2bf(b.z); rb.us[3] = f2bf(b.w);
  *(uint2*)(Wcat + (size_t)r * 1536 + c4) = ra.u2;
  *(uint2*)(Wcat + (size_t)r * 1536 + 768 + c4) = rb.u2;
}

// pack x -> bf16 (one thread per 8 floats)
__device__ __forceinline__ void packx_body(int blk, const float* __restrict__ x,
                                           unsigned short* __restrict__ xb) {
  size_t gid = (size_t)blk * 256 + threadIdx.x;
  const float4* x4 = (const float4*)x;
  float4 v0 = x4[gid * 2], v1 = x4[gid * 2 + 1];
  union { unsigned short us[8]; uint4 u4; } r;
  r.us[0] = f2bf(v0.x); r.us[1] = f2bf(v0.y); r.us[2] = f2bf(v0.z); r.us[3] = f2bf(v0.w);
  r.us[4] = f2bf(v1.x); r.us[5] = f2bf(v1.y); r.us[6] = f2bf(v1.z); r.us[7] = f2bf(v1.w);
  ((uint4*)xb)[gid] = r.u4;
}

// BT-format bf16 MFMA GEMM body: C[m][n] = sum_k A[m][k] * B[n][k]
// Tile (64*TMD) x (64*TND), 4 waves, BK=64, glds16 staging.
// Double-buffered LDS, prefetch-before-compute, one fused
// "s_waitcnt vmcnt(0); s_barrier" per K-step.
// LDS bank-conflict swizzle (both-sides-or-neither): LDS dest stays linear
// (glds16 requirement); the 16B slot within each row is permuted on the
// GLOBAL source side (scol) and identically on the fragment-read side, so
// a wave's 64 b128 reads hit all 32 banks evenly (8 words/bank = minimum).
// bid & 7 -> batch (XCD affinity).
// EPI 0: store bf16.
// EPI 1: f32 epilogue gate*acc + gate*(b1+b2) + x.
// EPI 2: bf16 store scaled by per-column inv-colsum (b1v = csp partials [b][32][768]).
template <int TMD, int TND, int EPI>
__device__ __forceinline__ void gemm_body(
    unsigned short* As, unsigned short* Bs, int bid,
    const unsigned short* __restrict__ A, const unsigned short* __restrict__ B,
    void* __restrict__ Cout, int K, int lda, int ldb, int ldc, int ntx,
    long long sA, long long sB, long long sC,
    const float* __restrict__ wg, const float* __restrict__ b1v,
    const float* __restrict__ b2v, const float* __restrict__ xres) {
  constexpr int TM = 64 * TMD, TN = 64 * TND;
  constexpr int ASZ = TM * 64, BSZ = TN * 64;  // shorts per LDS buffer
  __shared__ float csi[64 * TND];              // EPI==2: inv colsum per C column
  const int t = threadIdx.x, w = t >> 6, lane = t & 63;
  const int bz = bid & 7;
  const int r = bid >> 3;
  const int by = r / ntx, bx = r - by * ntx;
  const int m0 = by * TM, n0 = bx * TN;
  const unsigned short* Ab = A + (size_t)bz * sA;
  const unsigned short* Bb = B + (size_t)bz * sB;
  const int srow = lane >> 3;          // 0..7 (row within 8-row chunk)
  // swizzled 16B slot: slot' = slot ^ (row&7)
  const int scol = (((lane & 7) ^ (lane >> 3)) * 8);

  auto stage = [&](int buf, int k0) {
    unsigned short* Ad = As + buf * ASZ;
    unsigned short* Bd = Bs + buf * BSZ;
#pragma unroll
    for (int l = 0; l < 2 * TND; ++l) {
      int chunk = l * 4 + w;
      int row = chunk * 8 + srow;
      glds16(Bb + (size_t)(n0 + row) * ldb + k0 + scol,
             (char*)Bd + chunk * 1024 + lane * 16);
    }
#pragma unroll
    for (int l = 0; l < 2 * TMD; ++l) {
      int chunk = l * 4 + w;
      int row = chunk * 8 + srow;
      glds16(Ab + (size_t)(m0 + row) * lda + k0 + scol,
             (char*)Ad + chunk * 1024 + lane * 16);
    }
  };

  stage(0, 0);

  if (EPI == 2) {
    // merge 32 colsum partials -> 1/sum for this block's output columns
    for (int c = t; c < TN; c += 256) {
      const float* cp = b1v + (size_t)bz * 32 * DIMD + n0 + c;
      float s = 0.f;
#pragma unroll
      for (int p = 0; p < 32; ++p) s += cp[(size_t)p * DIMD];
      csi[c] = 1.0f / s;
    }
  }

  accf4 zero = {0.f, 0.f, 0.f, 0.f};
  accf4 acc[2 * TMD][2 * TND];
#pragma unroll
  for (int i = 0; i < 2 * TMD; ++i)
#pragma unroll
    for (int j = 0; j < 2 * TND; ++j) acc[i][j] = zero;

  const int wm = (w & 1) * (32 * TMD), wn = (w >> 1) * (32 * TND);
  const int lm = lane & 15, qd = lane >> 4;
  const int lsw = (lm & 7) << 3;       // read-side swizzle XOR (in shorts)

  // drains stage(0) (syncthreads implies vmcnt(0)+lgkmcnt(0)) and makes csi visible
  __syncthreads();

  const int nt = K / 64;
  int cur = 0;
#pragma unroll 2
  for (int tt = 0; tt < nt; ++tt) {
    if (tt + 1 < nt) stage(cur ^ 1, (tt + 1) * 64);
    const unsigned short* Ar = As + cur * ASZ;
    const unsigned short* Br = Bs + cur * BSZ;
#pragma unroll
    for (int kc = 0; kc < 2; ++kc) {
      bfrag8 av[2 * TMD], bv[2 * TND];
      const int kslot = (((kc << 2) | qd) << 3) ^ lsw;   // swizzled 16B slot
#pragma unroll
      for (int i = 0; i < 2 * TMD; ++i)
        av[i] = *(const bfrag8*)(Ar + (wm + i * 16 + lm) * 64 + kslot);
#pragma unroll
      for (int j = 0; j < 2 * TND; ++j)
        bv[j] = *(const bfrag8*)(Br + (wn + j * 16 + lm) * 64 + kslot);
      __builtin_amdgcn_s_setprio(1);
#pragma unroll
      for (int i = 0; i < 2 * TMD; ++i)
#pragma unroll
        for (int j = 0; j < 2 * TND; ++j)
          acc[i][j] = __builtin_amdgcn_mfma_f32_16x16x32_bf16(av[i], bv[j], acc[i][j], 0, 0, 0);
      __builtin_amdgcn_s_setprio(0);
    }
    if (tt + 1 < nt) {
      // fused: wait own stage loads, then workgroup barrier. All ds_reads of
      // buf[cur] were consumed by MFMAs above, so buf[cur] is free to restage.
      asm volatile("s_waitcnt vmcnt(0)\n\ts_barrier" ::: "memory");
    }
    cur ^= 1;
  }

  if (EPI == 0) {
    unsigned short* Cb = (unsigned short*)Cout + (size_t)bz * sC;
#pragma unroll
    for (int i = 0; i < 2 * TMD; ++i)
#pragma unroll
      for (int j = 0; j < 2 * TND; ++j) {
        int col = n0 + wn + j * 16 + lm;
#pragma unroll
        for (int rr = 0; rr < 4; ++rr) {
          int row = m0 + wm + i * 16 + qd * 4 + rr;
          Cb[(size_t)row * ldc + col] = f2bf(acc[i][j][rr]);
        }
      }
  } else if (EPI == 1) {
    float gate = 1.f / (1.f + __expf(-wg[0]));
    float* Co = (float*)Cout + (size_t)bz * sC;
    const float* Xr = xres + (size_t)bz * sC;
#pragma unroll
    for (int j = 0; j < 2 * TND; ++j) {
      int col = n0 + wn + j * 16 + lm;
      float gb = gate * (b1v[col] + b2v[col]);
#pragma unroll
      for (int i = 0; i < 2 * TMD; ++i)
#pragma unroll
        for (int rr = 0; rr < 4; ++rr) {
          int row = m0 + wm + i * 16 + qd * 4 + rr;
          size_t idx = (size_t)row * ldc + col;
          Co[idx] = gate * acc[i][j][rr] + gb + Xr[idx];
        }
    }
  } else {
    unsigned short* Cb = (unsigned short*)Cout + (size_t)bz * sC;
#pragma unroll
    for (int j = 0; j < 2 * TND; ++j) {
      int lc = wn + j * 16 + lm;
      int col = n0 + lc;
      float ci = csi[lc];
#pragma unroll
      for (int i = 0; i < 2 * TMD; ++i)
#pragma unroll
        for (int rr = 0; rr < 4; ++rr) {
          int row = m0 + wm + i * 16 + qd * 4 + rr;
          Cb[(size_t)row * ldc + col] = f2bf(acc[i][j][rr] * ci);
        }
    }
  }
}

// ---------------------------------------------------------------------------
// stage1: fused rowsum + exp + transpose (+ packw)
// One block = 64 tokens x all 768 dims: reads x once, computes exp once,
// does the feature-softmax rowsum in-block (quad shuffle), emits
// Kt = exp*rowsum_inv and Qt = raw exp bits (token-softmax deferred to
// S-gemm epilogue via csp partials). Replaces the old prep rowsum pass
// (second full read of x2/x3 + second exp) and one launch.
// blocks [0,nsm): smkq (attn = blk>>8 selects A/B set, 256 blocks each)
// blocks [nsm, nsm+npw): packw
// ---------------------------------------------------------------------------
__global__ __launch_bounds__(256) void stage1_kernel(
    const float* __restrict__ xA, unsigned short* __restrict__ KtA,
    unsigned short* __restrict__ QtA, float* __restrict__ cspA,
    const float* __restrict__ xB, unsigned short* __restrict__ KtB,
    unsigned short* __restrict__ QtB, float* __restrict__ cspB,
    int nsm,
    const float* __restrict__ W1, const float* __restrict__ W2,
    unsigned short* __restrict__ Wcat, int npw) {
  int blk = blockIdx.x;
  if (blk >= nsm) {
    if (blk < nsm + npw) packw_body(blk - nsm, W1, W2, Wcat);
    return;
  }
  __shared__ float rowsi[64];
  __shared__ __align__(16) unsigned short etile[768 * 72];  // stride 144B: 16B-aligned rows
  const int sel = blk >> 8;
  const float* xin = sel ? xB : xA;
  unsigned short* Kt = sel ? KtB : KtA;
  unsigned short* Qt = sel ? QtB : QtA;
  float* csp = sel ? cspB : cspA;
  const int lb = blk & 255;
  const int b = (lb >> 5) & 7, ntile = lb & 31, n0 = ntile * 64;
  const int t = threadIdx.x;

  // phase A: exp + transposed LDS store + rowsum partial (4 threads/token)
  const int tok = t >> 2, seg = t & 3;
  const float* row = xin + ((size_t)b * NTOK + n0 + tok) * DIMD + seg * 192;
  float s = 0.f;
#pragma unroll 12
  for (int j = 0; j < 48; ++j) {
    float4 v = *(const float4*)(row + j * 4);
    float e0 = __expf(v.x), e1 = __expf(v.y), e2 = __expf(v.z), e3 = __expf(v.w);
    s += (e0 + e1) + (e2 + e3);
    int d = seg * 192 + j * 4;
    etile[(d + 0) * 72 + tok] = f2bf(e0);
    etile[(d + 1) * 72 + tok] = f2bf(e1);
    etile[(d + 2) * 72 + tok] = f2bf(e2);
    etile[(d + 3) * 72 + tok] = f2bf(e3);
  }
  s += __shfl_xor(s, 1, 64);
  s += __shfl_xor(s, 2, 64);
  if (seg == 0) rowsi[tok] = 1.0f / s;
  __syncthreads();

  // phase B: read back 8-token groups, write Kt (scaled) + Qt (raw) + csp
#pragma unroll 4
  for (int q = 0; q < 24; ++q) {
    int dl = (t >> 3) + q * 32;                  // 0..767
    int g = t & 7;                               // 8 tokens each
    uint4 e8 = *(const uint4*)(etile + dl * 72 + g * 8);
    float ef[8];
    ef[0] = __uint_as_float(e8.x << 16); ef[1] = __uint_as_float(e8.x & 0xffff0000u);
    ef[2] = __uint_as_float(e8.y << 16); ef[3] = __uint_as_float(e8.y & 0xffff0000u);
    ef[4] = __uint_as_float(e8.z << 16); ef[5] = __uint_as_float(e8.z & 0xffff0000u);
    ef[6] = __uint_as_float(e8.w << 16); ef[7] = __uint_as_float(e8.w & 0xffff0000u);
    float4 r0 = *(const float4*)&rowsi[g * 8];
    float4 r1 = *(const float4*)&rowsi[g * 8 + 4];
    union { unsigned short us[8]; uint4 u4; } ko;
    ko.us[0] = f2bf(ef[0] * r0.x); ko.us[1] = f2bf(ef[1] * r0.y);
    ko.us[2] = f2bf(ef[2] * r0.z); ko.us[3] = f2bf(ef[3] * r0.w);
    ko.us[4] = f2bf(ef[4] * r1.x); ko.us[5] = f2bf(ef[5] * r1.y);
    ko.us[6] = f2bf(ef[6] * r1.z); ko.us[7] = f2bf(ef[7] * r1.w);
    size_t orow = ((size_t)b * DIMD + dl) * NTOK + n0 + g * 8;
    *(uint4*)(Kt + orow) = ko.u4;
    *(uint4*)(Qt + orow) = e8;                   // raw exp bits
    // colsum partial over this tile's 64 tokens for dim dl
    float cs = ((ef[0] + ef[1]) + (ef[2] + ef[3])) + ((ef[4] + ef[5]) + (ef[6] + ef[7]));
    cs += __shfl_xor(cs, 1, 64);
    cs += __shfl_xor(cs, 2, 64);
    cs += __shfl_xor(cs, 4, 64);
    if (g == 0) csp[((size_t)b * 32 + ntile) * DIMD + dl] = cs;
  }
}

// standalone GEMM (final epilogue)
template <int TMD, int TND, int EPI>
__global__ __launch_bounds__(256) void mfma_bt(
    const unsigned short* __restrict__ A, const unsigned short* __restrict__ B,
    void* __restrict__ Cout, int K, int lda, int ldb, int ldc, int ntx,
    long long sA, long long sB, long long sC,
    const float* __restrict__ wg, const float* __restrict__ b1v,
    const float* __restrict__ b2v, const float* __restrict__ xres) {
  __shared__ __align__(16) unsigned short As[2 * 64 * TMD * 64];
  __shared__ __align__(16) unsigned short Bs[2 * 64 * TND * 64];
  gemm_body<TMD, TND, EPI>(As, Bs, blockIdx.x, A, B, Cout, K, lda, ldb, ldc, ntx,
                           sA, sB, sC, wg, b1v, b2v, xres);
}

// S-gemm (both attentions in one launch when grid=576): blocks [0,288) do
// S_a = Kta . Qta^T * diag(cspa^-1); [288,576) do S_b -> Cb.
__global__ __launch_bounds__(256) void sgemm_s(
    const unsigned short* __restrict__ KtA, const unsigned short* __restrict__ QtA,
    const float* __restrict__ cspA,
    const unsigned short* __restrict__ KtB, const unsigned short* __restrict__ QtB,
    const float* __restrict__ cspB,
    unsigned short* __restrict__ Ca, unsigned short* __restrict__ Cb) {
  __shared__ __align__(16) unsigned short As[2 * 128 * 64];
  __shared__ __align__(16) unsigned short Bs[2 * 128 * 64];
  bool second = blockIdx.x >= 288;
  const unsigned short* A = second ? KtB : KtA;
  const unsigned short* B = second ? QtB : QtA;
  const float* csp = second ? cspB : cspA;
  unsigned short* C = second ? Cb : Ca;
  int blk = second ? (blockIdx.x - 288) : blockIdx.x;
  gemm_body<2, 2, 2>(As, Bs, blk, A, B, C, NTOK, NTOK, NTOK, 1536, 6,
                     768LL * NTOK, 768LL * NTOK, 768LL * 1536,
                     nullptr, csp, nullptr, nullptr);
}

// s2 (Bt = Wcat . Scat^T, 288 blocks, 128x128) + pack_x (6144 BW-bound blocks;
// must stay in this launch: xb aliases the Kt1 region, dead only after sgemm_s)
__global__ __launch_bounds__(256) void s2_packx_kernel(
    const unsigned short* __restrict__ Wcat, const unsigned short* __restrict__ Scat,
    unsigned short* __restrict__ Bt, const float* __restrict__ x,
    unsigned short* __restrict__ xb) {
  __shared__ __align__(16) unsigned short As[2 * 128 * 64];
  __shared__ __align__(16) unsigned short Bs[2 * 128 * 64];
  int blk = blockIdx.x;
  if (blk < 288) {
    gemm_body<2, 2, 0>(As, Bs, blk, Wcat, Scat, Bt, 1536, 1536, 1536, 768, 6,
                       0LL, 768LL * 1536, 768LL * 768,
                       nullptr, nullptr, nullptr, nullptr);
  } else {
    packx_body(blk - 288, x, xb);
  }
}

// ---------------------------------------------------------------------------
// launch
// ---------------------------------------------------------------------------
extern "C" void kernel_launch(void* const* d_in, const int* in_sizes, int n_in,
                              void* d_out, int out_size, void* d_ws, size_t ws_size,
                              hipStream_t stream) {
  const float* x  = (const float*)d_in[0];
  const float* x2 = (const float*)d_in[1];
  const float* x3 = (const float*)d_in[2];
  const float* W1 = (const float*)d_in[3];
  const float* b1 = (const float*)d_in[4];
  const float* W2 = (const float*)d_in[5];
  const float* b2 = (const float*)d_in[6];
  const float* w  = (const float*)d_in[7];
  float* out = (float*)d_out;
  char* ws = (char*)d_ws;

  dim3 blk(256);
  const bool merged = ws_size >= 123600896ull;

  if (merged) {
    // layout (bytes): Kt1 0 | Qt1 25165824 | Kt2 50331648 | Qt2 75497472 |
    // Scat 100663296 | Wcat 119537664 | csp1 121896960 | csp2 122683392 |
    // end 123469824. Bt aliases Kt1 (dead after sgemm_s); xb aliases Kt1+9437184.
    unsigned short* Kt1  = (unsigned short*)(ws + 0);
    unsigned short* Qt1  = (unsigned short*)(ws + 25165824);
    unsigned short* Kt2  = (unsigned short*)(ws + 50331648);
    unsigned short* Qt2  = (unsigned short*)(ws + 75497472);
    unsigned short* Scat = (unsigned short*)(ws + 100663296);
    unsigned short* Wcat = (unsigned short*)(ws + 119537664);
    float* csp1 = (float*)(ws + 121896960);
    float* csp2 = (float*)(ws + 122683392);
    unsigned short* Bt = (unsigned short*)(ws + 0);
    unsigned short* xb = (unsigned short*)(ws + 9437184);

    stage1_kernel<<<1088, blk, 0, stream>>>(x2, Kt1, Qt1, csp1,
                                            x3, Kt2, Qt2, csp2, 512,
                                            W1, W2, Wcat, 576);
    sgemm_s<<<576, blk, 0, stream>>>(Kt1, Qt1, csp1, Kt2, Qt2, csp2, Scat, Scat + 768);
    s2_packx_kernel<<<6432, blk, 0, stream>>>(Wcat, Scat, Bt, x, xb);
    mfma_bt<2, 2, 1><<<768, blk, 0, stream>>>(xb, Bt, out, DIMD, DIMD, DIMD, DIMD, 6,
                                              (long long)NTOK * DIMD, 768LL * 768,
                                              (long long)NTOK * DIMD, w, b1, b2, x);
  } else {
    // sequential fallback within the proven 107 MB footprint:
    // Kt 0 | Qt 25165824 | Scat 50331648 | Bt 69206016 | xb 78643200 |
    // Wcat 103809024 (end 106168320). csp alias the Bt region (dead until s2).
    unsigned short* Kt   = (unsigned short*)(ws + 0);
    unsigned short* Qt   = (unsigned short*)(ws + 25165824);
    unsigned short* Scat = (unsigned short*)(ws + 50331648);
    unsigned short* Bt   = (unsigned short*)(ws + 69206016);
    float* csp1 = (float*)(ws + 69206016);
    float* csp2 = (float*)(ws + 69992448);
    unsigned short* xb   = (unsigned short*)(ws + 78643200);
    unsigned short* Wcat = (unsigned short*)(ws + 103809024);

    stage1_kernel<<<832, blk, 0, stream>>>(x2, Kt, Qt, csp1,
                                           x2, Kt, Qt, csp1, 256,
                                           W1, W2, Wcat, 576);
    sgemm_s<<<288, blk, 0, stream>>>(Kt, Qt, csp1, Kt, Qt, csp1, Scat, Scat);
    stage1_kernel<<<256, blk, 0, stream>>>(x3, Kt, Qt, csp2,
                                           x3, Kt, Qt, csp2, 256,
                                           W1, W2, Wcat, 0);
    sgemm_s<<<288, blk, 0, stream>>>(Kt, Qt, csp2, Kt, Qt, csp2, Scat + 768, Scat + 768);
    s2_packx_kernel<<<6432, blk, 0, stream>>>(Wcat, Scat, Bt, x, xb);
    mfma_bt<2, 2, 1><<<768, blk, 0, stream>>>(xb, Bt, out, DIMD, DIMD, DIMD, DIMD, 6,
                                              (long long)NTOK * DIMD, 768LL * 768,
                                              (long long)NTOK * DIMD, w, b1, b2, x);
  }
}